// Round 1
// baseline (340.860 us; speedup 1.0000x reference)
//
#include <hip/hip_runtime.h>

#define NE 40943
#define NR 18
#define ED 200
#define KWC 9
#define OC 32
#define WOUT 192
#define KOC 288      // KW*OC
#define KFEAT 6144   // OC*WOUT
#define KH 224       // padded K (ED 200 -> 224) for gemm2
#define G1_LD 136    // 128 + 8 pad (bf16 elems)
#define G2_LD 40     // 32 + 8 pad

typedef unsigned short u16;
typedef unsigned int u32;
typedef __bf16 bf16x8 __attribute__((ext_vector_type(8)));
typedef float f32x4 __attribute__((ext_vector_type(4)));
typedef u16 u16x8 __attribute__((ext_vector_type(8)));
typedef u16 u16x4 __attribute__((ext_vector_type(4)));

__device__ __forceinline__ u16 f2bf(float f) {
  u32 u = __builtin_bit_cast(u32, f);
  u32 r = (u + 0x7fffu + ((u >> 16) & 1u)) >> 16;
  return (u16)r;
}

// Kr[rel][j] = sum_d R[rel][d] * W1[d][j] + b1[j]   (18 x 288, f32)
__global__ void prep_k_kernel(const float* __restrict__ R,
                              const float* __restrict__ W1,
                              const float* __restrict__ b1,
                              float* __restrict__ Kr) {
  int rel = blockIdx.x;
  int j = threadIdx.x;  // 0..287
  float acc = b1[j];
  const float* rrow = R + rel * ED;
  for (int d = 0; d < ED; ++d) acc += rrow[d] * W1[d * KOC + j];
  Kr[rel * KOC + j] = acc;
}

// feat[b][o*192+w] = sum_j e1[b][w+j] * Kr[r_idx[b]][j*32+o]  -> bf16
__global__ void prep_feat_kernel(const int* __restrict__ e1_idx,
                                 const int* __restrict__ r_idx,
                                 const float* __restrict__ E,
                                 const float* __restrict__ Kr,
                                 u16* __restrict__ feat) {
  __shared__ float e1s[ED];
  __shared__ float ks[KOC];
  int b = blockIdx.y;
  int t = threadIdx.x;
  int e1 = e1_idx[b];
  int r = r_idx[b];
  if (t < ED) e1s[t] = E[(size_t)e1 * ED + t];
  ks[t] = Kr[r * KOC + t];
  if (t < KOC - 256) ks[256 + t] = Kr[r * KOC + 256 + t];
  __syncthreads();
  int i0 = (blockIdx.x * 256 + t) * 4;  // 4 consecutive i, same o (192%4==0)
  int o = i0 / WOUT;
  int w0 = i0 % WOUT;
  float a0 = 0.f, a1 = 0.f, a2 = 0.f, a3 = 0.f;
#pragma unroll
  for (int j = 0; j < KWC; ++j) {
    float kv = ks[j * OC + o];
    a0 += e1s[w0 + j] * kv;
    a1 += e1s[w0 + 1 + j] * kv;
    a2 += e1s[w0 + 2 + j] * kv;
    a3 += e1s[w0 + 3 + j] * kv;
  }
  u16x4 st = {f2bf(a0), f2bf(a1), f2bf(a2), f2bf(a3)};
  *(u16x4*)(feat + (size_t)b * KFEAT + i0) = st;
}

// W2T[d][i] = W2[i][d] as bf16; rows d in [200,256) are zero
__global__ void conv_w2t_kernel(const float* __restrict__ W2, u16* __restrict__ W2T) {
  __shared__ float tile[32][33];
  int i0 = blockIdx.x * 32;
  int d0 = blockIdx.y * 32;
  int tx = threadIdx.x & 31;
  int ty = threadIdx.x >> 5;  // 0..7
#pragma unroll
  for (int rr = 0; rr < 4; ++rr) {
    int i = i0 + ty + rr * 8;
    int d = d0 + tx;
    float v = (d < ED) ? W2[(size_t)i * ED + d] : 0.f;
    tile[tx][ty + rr * 8] = v;  // tile[d_local][i_local]
  }
  __syncthreads();
#pragma unroll
  for (int rr = 0; rr < 4; ++rr) {
    int d = d0 + ty + rr * 8;
    int i = i0 + tx;
    W2T[(size_t)d * KFEAT + i] = f2bf(tile[ty + rr * 8][tx]);
  }
}

// Eb[n][0..223]: bf16(E[n][d]) for d<200 else 0
__global__ void conv_e_kernel(const float* __restrict__ E, u16* __restrict__ Eb) {
  int idx = blockIdx.x * 256 + threadIdx.x;
  const int total = NE * (KH / 4);
  if (idx >= total) return;
  int row = idx / (KH / 4);
  int c4 = (idx % (KH / 4)) * 4;
  u16x4 st = {0, 0, 0, 0};
  if (c4 < ED) {  // c4 in {0..196} fully valid; {200..220} zero — never straddles
    f32x4 v = *(const f32x4*)(E + (size_t)row * ED + c4);
    st[0] = f2bf(v[0]); st[1] = f2bf(v[1]); st[2] = f2bf(v[2]); st[3] = f2bf(v[3]);
  }
  *(u16x4*)(Eb + (size_t)row * KH + c4) = st;
}

// H[1024][224] = relu(feat @ W2 + b2) in bf16, cols>=200 zeroed
__global__ __launch_bounds__(256) void gemm1_kernel(
    const u16* __restrict__ A,   // feat [1024][6144]
    const u16* __restrict__ B,   // W2T  [256][6144]
    const float* __restrict__ b2,
    u16* __restrict__ H) {
  __shared__ u16 lA[64 * G1_LD];
  __shared__ u16 lB[64 * G1_LD];
  const int t = threadIdx.x;
  const int m0 = blockIdx.y * 64;
  const int n0 = blockIdx.x * 64;
  const int wave = t >> 6, lane = t & 63;
  const int wm = (wave >> 1) * 32, wn = (wave & 1) * 32;
  const int lr = lane & 15, lq = lane >> 4;
  f32x4 zero = {0.f, 0.f, 0.f, 0.f};
  f32x4 acc[2][2];
#pragma unroll
  for (int i = 0; i < 2; ++i)
#pragma unroll
    for (int j = 0; j < 2; ++j) acc[i][j] = zero;

  for (int k0 = 0; k0 < KFEAT; k0 += 128) {
#pragma unroll
    for (int s = 0; s < 4; ++s) {
      int v = t + s * 256;
      int r = v >> 4;
      int c8 = (v & 15) * 8;
      *(u16x8*)(lA + r * G1_LD + c8) = *(const u16x8*)(A + (size_t)(m0 + r) * KFEAT + k0 + c8);
      *(u16x8*)(lB + r * G1_LD + c8) = *(const u16x8*)(B + (size_t)(n0 + r) * KFEAT + k0 + c8);
    }
    __syncthreads();
#pragma unroll
    for (int kk = 0; kk < 128; kk += 32) {
      bf16x8 af[2], bfv[2];
#pragma unroll
      for (int mi = 0; mi < 2; ++mi)
        af[mi] = *(const bf16x8*)(lA + (wm + mi * 16 + lr) * G1_LD + kk + lq * 8);
#pragma unroll
      for (int ni = 0; ni < 2; ++ni)
        bfv[ni] = *(const bf16x8*)(lB + (wn + ni * 16 + lr) * G1_LD + kk + lq * 8);
#pragma unroll
      for (int mi = 0; mi < 2; ++mi)
#pragma unroll
        for (int ni = 0; ni < 2; ++ni)
          acc[mi][ni] = __builtin_amdgcn_mfma_f32_16x16x32_bf16(af[mi], bfv[ni], acc[mi][ni], 0, 0, 0);
    }
    __syncthreads();
  }
#pragma unroll
  for (int mi = 0; mi < 2; ++mi) {
    int row = m0 + wm + mi * 16 + lq * 4;
#pragma unroll
    for (int ni = 0; ni < 2; ++ni) {
      int col = n0 + wn + ni * 16 + lr;
      if (col < KH) {
        float bv = (col < ED) ? b2[col] : 0.f;
#pragma unroll
        for (int i = 0; i < 4; ++i) {
          float vv = acc[mi][ni][i] + bv;
          vv = vv > 0.f ? vv : 0.f;
          if (col >= ED) vv = 0.f;
          H[(size_t)(row + i) * KH + col] = f2bf(vv);
        }
      }
    }
  }
}

// out[b][n] = sum_d H[b][d]*Eb[n][d] + bias[n]   (f32 out)
__global__ __launch_bounds__(256) void gemm2_kernel(
    const u16* __restrict__ Hb,  // [1024][224]
    const u16* __restrict__ Eb,  // [40943][224]
    const float* __restrict__ bias,
    float* __restrict__ out) {
  __shared__ u16 lA[128 * G2_LD];
  __shared__ u16 lB[128 * G2_LD];
  const int t = threadIdx.x;
  const int m0 = blockIdx.y * 128;
  const int n0 = blockIdx.x * 128;
  const int wave = t >> 6, lane = t & 63;
  const int wm = (wave >> 1) * 64, wn = (wave & 1) * 64;
  const int lr = lane & 15, lq = lane >> 4;
  f32x4 zero = {0.f, 0.f, 0.f, 0.f};
  f32x4 acc[4][4];
#pragma unroll
  for (int i = 0; i < 4; ++i)
#pragma unroll
    for (int j = 0; j < 4; ++j) acc[i][j] = zero;

  for (int k0 = 0; k0 < KH; k0 += 32) {
#pragma unroll
    for (int s = 0; s < 2; ++s) {
      int v = t + s * 256;
      int r = v >> 2;
      int c8 = (v & 3) * 8;
      *(u16x8*)(lA + r * G2_LD + c8) = *(const u16x8*)(Hb + (size_t)(m0 + r) * KH + k0 + c8);
      int gr = n0 + r;
      u16x8 bv = {0, 0, 0, 0, 0, 0, 0, 0};
      if (gr < NE) bv = *(const u16x8*)(Eb + (size_t)gr * KH + k0 + c8);
      *(u16x8*)(lB + r * G2_LD + c8) = bv;
    }
    __syncthreads();
    bf16x8 af[4], bfv[4];
#pragma unroll
    for (int mi = 0; mi < 4; ++mi)
      af[mi] = *(const bf16x8*)(lA + (wm + mi * 16 + lr) * G2_LD + lq * 8);
#pragma unroll
    for (int ni = 0; ni < 4; ++ni)
      bfv[ni] = *(const bf16x8*)(lB + (wn + ni * 16 + lr) * G2_LD + lq * 8);
#pragma unroll
    for (int mi = 0; mi < 4; ++mi)
#pragma unroll
      for (int ni = 0; ni < 4; ++ni)
        acc[mi][ni] = __builtin_amdgcn_mfma_f32_16x16x32_bf16(af[mi], bfv[ni], acc[mi][ni], 0, 0, 0);
    __syncthreads();
  }
#pragma unroll
  for (int mi = 0; mi < 4; ++mi) {
    int row = m0 + wm + mi * 16 + lq * 4;
#pragma unroll
    for (int ni = 0; ni < 4; ++ni) {
      int col = n0 + wn + ni * 16 + lr;
      if (col < NE) {
        float bv = bias[col];
#pragma unroll
        for (int i = 0; i < 4; ++i)
          out[(size_t)(row + i) * NE + col] = acc[mi][ni][i] + bv;
      }
    }
  }
}

extern "C" void kernel_launch(void* const* d_in, const int* in_sizes, int n_in,
                              void* d_out, int out_size, void* d_ws, size_t ws_size,
                              hipStream_t stream) {
  const int* e1_idx = (const int*)d_in[0];
  const int* r_idx = (const int*)d_in[1];
  const float* W1 = (const float*)d_in[2];
  const float* b1 = (const float*)d_in[3];
  const float* W2 = (const float*)d_in[4];
  const float* b2 = (const float*)d_in[5];
  const float* bias_logits = (const float*)d_in[6];
  const float* E = (const float*)d_in[7];
  const float* R = (const float*)d_in[8];
  float* out = (float*)d_out;

  char* ws = (char*)d_ws;
  float* Kr = (float*)ws;                              // 18*288*4 = 20,736
  u16* feat = (u16*)(ws + 32768);                      // 1024*6144*2 = 12,582,912
  u16* W2T = (u16*)(ws + 32768 + 12582912);            // 256*6144*2 = 3,145,728
  u16* Hb = (u16*)(ws + 32768 + 12582912 + 3145728);   // 1024*224*2 = 458,752
  u16* Eb = (u16*)(ws + 32768 + 12582912 + 3145728 + 458752);  // 40943*224*2 = 18,342,464

  prep_k_kernel<<<dim3(NR), dim3(KOC), 0, stream>>>(R, W1, b1, Kr);
  conv_w2t_kernel<<<dim3(KFEAT / 32, 256 / 32), dim3(256), 0, stream>>>(W2, W2T);
  conv_e_kernel<<<dim3((NE * (KH / 4) + 255) / 256), dim3(256), 0, stream>>>(E, Eb);
  prep_feat_kernel<<<dim3(KFEAT / 1024, 1024), dim3(256), 0, stream>>>(e1_idx, r_idx, E, Kr, feat);
  gemm1_kernel<<<dim3(4, 16), dim3(256), 0, stream>>>(feat, W2T, b2, Hb);
  gemm2_kernel<<<dim3((NE + 127) / 128, 8), dim3(256), 0, stream>>>(Hb, Eb, bias_logits, out);
}

// Round 2
// 320.444 us; speedup vs baseline: 1.0637x; 1.0637x over previous
//
#include <hip/hip_runtime.h>

#define NE 40943
#define NR 18
#define ED 200
#define KWC 9
#define OC 32
#define WOUT 192
#define KOC 288      // KW*OC
#define KH 224       // padded K (ED 200 -> 224) for gemm2
#define G2_LD 40     // 32 + 8 pad

typedef unsigned short u16;
typedef unsigned int u32;
typedef __bf16 bf16x8 __attribute__((ext_vector_type(8)));
typedef float f32x4 __attribute__((ext_vector_type(4)));
typedef u16 u16x8 __attribute__((ext_vector_type(8)));
typedef u16 u16x4 __attribute__((ext_vector_type(4)));

__device__ __forceinline__ u16 f2bf(float f) {
  u32 u = __builtin_bit_cast(u32, f);
  u32 r = (u + 0x7fffu + ((u >> 16) & 1u)) >> 16;
  return (u16)r;
}

// KrT[j*32+o][rel] = sum_d R[rel][d] * W1[d][j*32+o] + b1[j*32+o]   (288 x 18, f32)
__global__ void prep_k_kernel(const float* __restrict__ R,
                              const float* __restrict__ W1,
                              const float* __restrict__ b1,
                              float* __restrict__ KrT) {
  int rel = blockIdx.x;
  int j = threadIdx.x;  // 0..287
  float acc = b1[j];
  const float* rrow = R + rel * ED;
  for (int d = 0; d < ED; ++d) acc += rrow[d] * W1[d * KOC + j];
  KrT[j * NR + rel] = acc;
}

// C[r][p][d] = sum_{j,o; 0<=p-j<192} KrT[j*32+o][r] * W2[(o*192+(p-j))*200 + d]
__global__ __launch_bounds__(256) void build_c_kernel(const float* __restrict__ KrT,
                                                      const float* __restrict__ W2,
                                                      float* __restrict__ C) {
  int p = blockIdx.x;   // 0..199
  int d = threadIdx.x;  // active < 200
  int jlo = p > (WOUT - 1) ? p - (WOUT - 1) : 0;
  int jhi = p < (KWC - 1) ? p : (KWC - 1);
  if (d < ED) {
    float acc[NR];
#pragma unroll
    for (int r = 0; r < NR; ++r) acc[r] = 0.f;
    for (int j = jlo; j <= jhi; ++j) {
      int w = p - j;
      const float* w2base = W2 + (size_t)w * ED + d;  // += o*192*200
      const float* kb = KrT + (j * OC) * NR;          // block-uniform -> s_load
#pragma unroll
      for (int o = 0; o < OC; ++o) {
        float w2v = w2base[(size_t)o * WOUT * ED];
#pragma unroll
        for (int r = 0; r < NR; ++r) acc[r] += kb[o * NR + r] * w2v;
      }
    }
#pragma unroll
    for (int r = 0; r < NR; ++r) C[((size_t)r * ED + p) * ED + d] = acc[r];
  }
}

// Hb[b][d] = bf16(relu(sum_p E[e1_idx[b]][p] * C[r_idx[b]][p][d] + b2[d])), pad d in [200,224) = 0
__global__ __launch_bounds__(256) void h_kernel(const int* __restrict__ e1_idx,
                                                const int* __restrict__ r_idx,
                                                const float* __restrict__ E,
                                                const float* __restrict__ C,
                                                const float* __restrict__ b2,
                                                u16* __restrict__ Hb) {
  __shared__ float e1s[ED];
  int b = blockIdx.x;
  int t = threadIdx.x;
  if (t < ED) e1s[t] = E[(size_t)e1_idx[b] * ED + t];
  __syncthreads();
  int r = r_idx[b];
  const float* Cr = C + (size_t)r * ED * ED;
  if (t < KH) {
    float acc = 0.f;
    if (t < ED) {
#pragma unroll 8
      for (int p = 0; p < ED; ++p) acc += e1s[p] * Cr[(size_t)p * ED + t];
      acc += b2[t];
      acc = acc > 0.f ? acc : 0.f;
    }
    Hb[(size_t)b * KH + t] = (t < ED) ? f2bf(acc) : (u16)0;
  }
}

// Eb[n][0..223]: bf16(E[n][d]) for d<200 else 0
__global__ void conv_e_kernel(const float* __restrict__ E, u16* __restrict__ Eb) {
  int idx = blockIdx.x * 256 + threadIdx.x;
  const int total = NE * (KH / 4);
  if (idx >= total) return;
  int row = idx / (KH / 4);
  int c4 = (idx % (KH / 4)) * 4;
  u16x4 st = {0, 0, 0, 0};
  if (c4 < ED) {  // c4 in {0..196} fully valid; {200..220} zero — never straddles
    f32x4 v = *(const f32x4*)(E + (size_t)row * ED + c4);
    st[0] = f2bf(v[0]); st[1] = f2bf(v[1]); st[2] = f2bf(v[2]); st[3] = f2bf(v[3]);
  }
  *(u16x4*)(Eb + (size_t)row * KH + c4) = st;
}

// out[b][n] = sum_d Hb[b][d]*Eb[n][d] + bias[n]   (f32 out)
__global__ __launch_bounds__(256) void gemm2_kernel(
    const u16* __restrict__ Hb,  // [1024][224]
    const u16* __restrict__ Eb,  // [40943][224]
    const float* __restrict__ bias,
    float* __restrict__ out) {
  __shared__ u16 lA[128 * G2_LD];
  __shared__ u16 lB[128 * G2_LD];
  const int t = threadIdx.x;
  const int m0 = blockIdx.y * 128;
  const int n0 = blockIdx.x * 128;
  const int wave = t >> 6, lane = t & 63;
  const int wm = (wave >> 1) * 64, wn = (wave & 1) * 64;
  const int lr = lane & 15, lq = lane >> 4;
  f32x4 zero = {0.f, 0.f, 0.f, 0.f};
  f32x4 acc[4][4];
#pragma unroll
  for (int i = 0; i < 4; ++i)
#pragma unroll
    for (int j = 0; j < 4; ++j) acc[i][j] = zero;

  for (int k0 = 0; k0 < KH; k0 += 32) {
#pragma unroll
    for (int s = 0; s < 2; ++s) {
      int v = t + s * 256;
      int r = v >> 2;
      int c8 = (v & 3) * 8;
      *(u16x8*)(lA + r * G2_LD + c8) = *(const u16x8*)(Hb + (size_t)(m0 + r) * KH + k0 + c8);
      int gr = n0 + r;
      u16x8 bv = {0, 0, 0, 0, 0, 0, 0, 0};
      if (gr < NE) bv = *(const u16x8*)(Eb + (size_t)gr * KH + k0 + c8);
      *(u16x8*)(lB + r * G2_LD + c8) = bv;
    }
    __syncthreads();
    bf16x8 af[4], bfv[4];
#pragma unroll
    for (int mi = 0; mi < 4; ++mi)
      af[mi] = *(const bf16x8*)(lA + (wm + mi * 16 + lr) * G2_LD + lq * 8);
#pragma unroll
    for (int ni = 0; ni < 4; ++ni)
      bfv[ni] = *(const bf16x8*)(lB + (wn + ni * 16 + lr) * G2_LD + lq * 8);
#pragma unroll
    for (int mi = 0; mi < 4; ++mi)
#pragma unroll
      for (int ni = 0; ni < 4; ++ni)
        acc[mi][ni] = __builtin_amdgcn_mfma_f32_16x16x32_bf16(af[mi], bfv[ni], acc[mi][ni], 0, 0, 0);
    __syncthreads();
  }
#pragma unroll
  for (int mi = 0; mi < 4; ++mi) {
    int row = m0 + wm + mi * 16 + lq * 4;
#pragma unroll
    for (int ni = 0; ni < 4; ++ni) {
      int col = n0 + wn + ni * 16 + lr;
      if (col < NE) {
        float bv = bias[col];
#pragma unroll
        for (int i = 0; i < 4; ++i)
          out[(size_t)(row + i) * NE + col] = acc[mi][ni][i] + bv;
      }
    }
  }
}

extern "C" void kernel_launch(void* const* d_in, const int* in_sizes, int n_in,
                              void* d_out, int out_size, void* d_ws, size_t ws_size,
                              hipStream_t stream) {
  const int* e1_idx = (const int*)d_in[0];
  const int* r_idx = (const int*)d_in[1];
  const float* W1 = (const float*)d_in[2];
  const float* b1 = (const float*)d_in[3];
  const float* W2 = (const float*)d_in[4];
  const float* b2 = (const float*)d_in[5];
  const float* bias_logits = (const float*)d_in[6];
  const float* E = (const float*)d_in[7];
  const float* R = (const float*)d_in[8];
  float* out = (float*)d_out;

  char* ws = (char*)d_ws;
  float* KrT = (float*)ws;                          // 288*18*4 = 20,736
  float* C = (float*)(ws + 32768);                  // 18*200*200*4 = 2,880,000
  u16* Hb = (u16*)(ws + 32768 + 2880000);           // 1024*224*2 = 458,752
  u16* Eb = (u16*)(ws + 32768 + 2880000 + 458752);  // 40943*224*2 = 18,342,464

  prep_k_kernel<<<dim3(NR), dim3(KOC), 0, stream>>>(R, W1, b1, KrT);
  build_c_kernel<<<dim3(ED), dim3(256), 0, stream>>>(KrT, W2, C);
  h_kernel<<<dim3(1024), dim3(256), 0, stream>>>(e1_idx, r_idx, E, C, b2, Hb);
  conv_e_kernel<<<dim3((NE * (KH / 4) + 255) / 256), dim3(256), 0, stream>>>(E, Eb);
  gemm2_kernel<<<dim3((NE + 127) / 128, 8), dim3(256), 0, stream>>>(Hb, Eb, bias_logits, out);
}